// Round 1
// baseline (1492.862 us; speedup 1.0000x reference)
//
#include <hip/hip_runtime.h>

// ---------------------------------------------------------------------------
// PointNet++ encoder, fp32, correctness-first.
// FPS / ball-query distance math uses non-contracted f32 ops to bit-match the
// numpy/XLA-CPU reference (these feed discrete index decisions).
// ---------------------------------------------------------------------------

#define DEV static __device__ __forceinline__

DEV float sqdist(float dx, float dy, float dz) {
    // ((dx*dx + dy*dy) + dz*dz) with no FMA contraction — must match numpy f32
    return __fadd_rn(__fadd_rn(__fmul_rn(dx, dx), __fmul_rn(dy, dy)), __fmul_rn(dz, dz));
}

DEV void fma4(float4& acc, float h, const float4& w) {
    acc.x = fmaf(h, w.x, acc.x); acc.y = fmaf(h, w.y, acc.y);
    acc.z = fmaf(h, w.z, acc.z); acc.w = fmaf(h, w.w, acc.w);
}

// ---------------- Farthest point sampling -----------------
// One block per batch. Point coords live in registers (K per thread) + LDS copy
// for the centroid broadcast. Emits new_xyz directly (indices not needed later).
template<int N, int NPOINT, int STRIDE, int T>
__global__ __launch_bounds__(T)
void fps_kernel(const float* __restrict__ xyz, float* __restrict__ new_xyz)
{
    constexpr int K  = (N + T - 1) / T;
    constexpr int NW = T / 64;
    const int b   = blockIdx.x;
    const int tid = threadIdx.x;
    __shared__ float px[N], py[N], pz[N];
    __shared__ float rv[NW];
    __shared__ int   ri[NW];
    __shared__ int   s_far;

    const float* base = xyz + (size_t)b * N * STRIDE;
    float rx[K], ry[K], rz[K], d[K];
#pragma unroll
    for (int k = 0; k < K; ++k) {
        int p = tid + k * T;
        float x = 0.f, y = 0.f, z = 0.f;
        if (N % T == 0 || p < N) {
            x = base[p * STRIDE + 0];
            y = base[p * STRIDE + 1];
            z = base[p * STRIDE + 2];
            px[p] = x; py[p] = y; pz[p] = z;
        }
        rx[k] = x; ry[k] = y; rz[k] = z;
        d[k] = 1e10f;   // matches reference init 10000000000.0
    }
    if (tid == 0) s_far = 0;
    __syncthreads();

    int far = 0;
    float* out = new_xyz + (size_t)b * NPOINT * 3;
    for (int s = 0; s < NPOINT; ++s) {
        float cx = px[far], cy = py[far], cz = pz[far];
        if (tid == 0) { out[s * 3 + 0] = cx; out[s * 3 + 1] = cy; out[s * 3 + 2] = cz; }
        float bestv = -1.0f; int besti = 0x7fffffff;
#pragma unroll
        for (int k = 0; k < K; ++k) {
            int p = tid + k * T;
            if (N % T == 0 || p < N) {
                float d2 = sqdist(rx[k] - cx, ry[k] - cy, rz[k] - cz);
                d[k] = fminf(d[k], d2);
                if (d[k] > bestv) { bestv = d[k]; besti = p; }  // strict > keeps lowest p
            }
        }
        // wave argmax (value desc, index asc on ties)
#pragma unroll
        for (int off = 1; off < 64; off <<= 1) {
            float ov = __shfl_xor(bestv, off);
            int   oi = __shfl_xor(besti, off);
            if (ov > bestv || (ov == bestv && oi < besti)) { bestv = ov; besti = oi; }
        }
        if ((tid & 63) == 0) { rv[tid >> 6] = bestv; ri[tid >> 6] = besti; }
        __syncthreads();
        if (tid == 0) {
            float bv = rv[0]; int bi = ri[0];
#pragma unroll
            for (int w = 1; w < NW; ++w)
                if (rv[w] > bv || (rv[w] == bv && ri[w] < bi)) { bv = rv[w]; bi = ri[w]; }
            s_far = bi;
        }
        __syncthreads();
        far = s_far;
    }
}

// ---------------- Ball query -----------------
// One wave per center; ordered compaction of the first NSAMP in-radius indices
// (ascending index order == reference's sort-based selection), pad with first.
template<int N, int NSAMP, int STRIDE>
__global__ __launch_bounds__(256)
void bq_kernel(const float* __restrict__ xyz, const float* __restrict__ newxyz,
               int* __restrict__ gidx, float r2, int S, int total)
{
    const int wid = blockIdx.x * 4 + (threadIdx.x >> 6);
    if (wid >= total) return;
    const int lane = threadIdx.x & 63;
    const int b = wid / S;
    const float cx = newxyz[(size_t)wid * 3 + 0];
    const float cy = newxyz[(size_t)wid * 3 + 1];
    const float cz = newxyz[(size_t)wid * 3 + 2];
    const float* base = xyz + (size_t)b * N * STRIDE;
    int* out = gidx + (size_t)wid * NSAMP;

    int count = 0, first = N - 1;
    constexpr int NCH = (N + 63) / 64;
    for (int ch = 0; ch < NCH; ++ch) {
        int p = ch * 64 + lane;
        bool pred = false;
        if (N % 64 == 0 || p < N) {
            float dx = base[p * STRIDE + 0] - cx;
            float dy = base[p * STRIDE + 1] - cy;
            float dz = base[p * STRIDE + 2] - cz;
            pred = sqdist(dx, dy, dz) < r2;
        }
        unsigned long long m = __ballot(pred);
        if (m) {
            if (count == 0) first = ch * 64 + __builtin_ctzll(m);
            int pos = count + __popcll(m & ((1ull << lane) - 1ull));
            if (pred && pos < NSAMP) out[pos] = p;
            count += __popcll(m);
            if (count >= NSAMP) break;
        }
    }
    if (count > NSAMP) count = NSAMP;
    for (int pos = count + lane; pos < NSAMP; pos += 64) out[pos] = first;
}

// ---------------- Grouped 2-layer MLP + maxpool -----------------
// One block per group. Gather (rel xyz ++ feats) into LDS, layer1 -> LDS,
// layer2 register-tiled 4pts x 4ch fused with maxpool.
// MODE 0: stage 1 — feats come from pc permuted [pc3..5, pc0..2], xyz stride 6.
// MODE 1: feats array (CIN-3 wide), xyz stride 3.
template<int NS, int CIN, int C1, int C2, int T, int NSRC, int MODE>
__global__ __launch_bounds__(T)
void sa_mlp_kernel(const float* __restrict__ sxyz, const float* __restrict__ sfeat,
                   const float* __restrict__ newxyz, const int* __restrict__ gidx,
                   const float* __restrict__ W1, const float* __restrict__ B1v,
                   const float* __restrict__ W2, const float* __restrict__ B2v,
                   float* __restrict__ outf, int S)
{
    constexpr int XS   = (MODE == 0) ? 6 : 3;
    constexpr int CF   = CIN - 3;
    constexpr int RC   = 4;
    constexpr int CT1  = C1 / RC;     // channel tiles, layer 1
    constexpr int NPB1 = T / CT1;
    constexpr int CT2  = C2 / RC;     // channel tiles, layer 2
    constexpr int NPB2 = T / CT2;

    __shared__ float xg[NS][CIN + 1];
    __shared__ __align__(16) float h1s[NS][C1];
    __shared__ int   gix[NS];
    __shared__ float ctr[3];
    __shared__ float mpart[NPB2 * C2];

    const int g   = blockIdx.x;
    const int b   = g / S;
    const int tid = threadIdx.x;

    if (tid < 3) ctr[tid] = newxyz[(size_t)g * 3 + tid];
    for (int i = tid; i < NS; i += T) gix[i] = gidx[(size_t)g * NS + i];
    __syncthreads();

    // gather: rel-xyz (exact f32 subs) ++ feats
    for (int i = tid; i < NS * CIN; i += T) {
        int p = i / CIN, k = i - p * CIN;
        int gi = gix[p];
        float v;
        if (k < 3) {
            v = sxyz[((size_t)b * NSRC + gi) * XS + k] - ctr[k];
        } else if (MODE == 0) {
            int j = k - 3;  // feats = [pc[:,3:6], pc[:,0:3]]
            v = sfeat[((size_t)b * NSRC + gi) * 6 + (j < 3 ? 3 + j : j - 3)];
        } else {
            v = sfeat[((size_t)b * NSRC + gi) * CF + (k - 3)];
        }
        xg[p][k] = v;
    }
    __syncthreads();

    { // layer 1: h1 = relu(xg @ W1 + b1)
        const int ct = tid % CT1, pb = tid / CT1;
        const int c0 = ct * RC;
        const float4 bb = *(const float4*)&B1v[c0];
        for (int p = pb; p < NS; p += NPB1) {
            float a0 = bb.x, a1 = bb.y, a2 = bb.z, a3 = bb.w;
            for (int k = 0; k < CIN; ++k) {
                float xv = xg[p][k];
                float4 w = *(const float4*)&W1[(size_t)k * C1 + c0];
                a0 = fmaf(xv, w.x, a0); a1 = fmaf(xv, w.y, a1);
                a2 = fmaf(xv, w.z, a2); a3 = fmaf(xv, w.w, a3);
            }
            float4 r;
            r.x = fmaxf(a0, 0.f); r.y = fmaxf(a1, 0.f);
            r.z = fmaxf(a2, 0.f); r.w = fmaxf(a3, 0.f);
            *(float4*)&h1s[p][c0] = r;
        }
    }
    __syncthreads();

    { // layer 2 + maxpool: out[c] = max_p relu(h1[p] @ W2 + b2)
        const int ct = tid % CT2, pb = tid / CT2;
        const int c0 = ct * RC;
        const float4 bb = *(const float4*)&B2v[c0];
        float m0 = 0.f, m1 = 0.f, m2 = 0.f, m3 = 0.f;  // relu >= 0 so 0-init == relu+max
        for (int p0 = pb * 4; p0 < NS; p0 += NPB2 * 4) {
            float4 acc0 = bb, acc1 = bb, acc2 = bb, acc3 = bb;
            for (int k = 0; k < C1; k += 4) {
                float4 hA = *(const float4*)&h1s[p0 + 0][k];
                float4 hB = *(const float4*)&h1s[p0 + 1][k];
                float4 hC = *(const float4*)&h1s[p0 + 2][k];
                float4 hD = *(const float4*)&h1s[p0 + 3][k];
                float4 w0 = *(const float4*)&W2[(size_t)(k + 0) * C2 + c0];
                float4 w1 = *(const float4*)&W2[(size_t)(k + 1) * C2 + c0];
                float4 w2 = *(const float4*)&W2[(size_t)(k + 2) * C2 + c0];
                float4 w3 = *(const float4*)&W2[(size_t)(k + 3) * C2 + c0];
                fma4(acc0, hA.x, w0); fma4(acc0, hA.y, w1); fma4(acc0, hA.z, w2); fma4(acc0, hA.w, w3);
                fma4(acc1, hB.x, w0); fma4(acc1, hB.y, w1); fma4(acc1, hB.z, w2); fma4(acc1, hB.w, w3);
                fma4(acc2, hC.x, w0); fma4(acc2, hC.y, w1); fma4(acc2, hC.z, w2); fma4(acc2, hC.w, w3);
                fma4(acc3, hD.x, w0); fma4(acc3, hD.y, w1); fma4(acc3, hD.z, w2); fma4(acc3, hD.w, w3);
            }
            m0 = fmaxf(m0, fmaxf(fmaxf(acc0.x, acc1.x), fmaxf(acc2.x, acc3.x)));
            m1 = fmaxf(m1, fmaxf(fmaxf(acc0.y, acc1.y), fmaxf(acc2.y, acc3.y)));
            m2 = fmaxf(m2, fmaxf(fmaxf(acc0.z, acc1.z), fmaxf(acc2.z, acc3.z)));
            m3 = fmaxf(m3, fmaxf(fmaxf(acc0.w, acc1.w), fmaxf(acc2.w, acc3.w)));
        }
        if (NPB2 == 1) {
            float* o = outf + (size_t)g * C2 + c0;
            o[0] = m0; o[1] = m1; o[2] = m2; o[3] = m3;
        } else {
            mpart[pb * C2 + c0 + 0] = m0; mpart[pb * C2 + c0 + 1] = m1;
            mpart[pb * C2 + c0 + 2] = m2; mpart[pb * C2 + c0 + 3] = m3;
            __syncthreads();
            for (int c = tid; c < C2; c += T) {
                float mm = mpart[c];
#pragma unroll
                for (int q = 1; q < NPB2; ++q) mm = fmaxf(mm, mpart[q * C2 + c]);
                outf[(size_t)g * C2 + c] = mm;
            }
        }
    }
}

// ---------------- Head part 1: per (b,point) 515->512->1024 MLP -----------------
__global__ __launch_bounds__(256)
void head1_kernel(const float* __restrict__ nxyz3, const float* __restrict__ feats3,
                  const float* __restrict__ w4a, const float* __restrict__ b4a,
                  const float* __restrict__ w4b, const float* __restrict__ b4b,
                  float* __restrict__ h4)
{
    const int g   = blockIdx.x;   // b*16 + p
    const int tid = threadIdx.x;
    __shared__ float xrow[515];
    __shared__ float h1s[512];
    for (int i = tid; i < 515; i += 256)
        xrow[i] = (i < 3) ? nxyz3[(size_t)g * 3 + i] : feats3[(size_t)g * 512 + (i - 3)];
    __syncthreads();
    for (int c = tid; c < 512; c += 256) {
        float a = b4a[c];
        for (int k = 0; k < 515; ++k) a = fmaf(xrow[k], w4a[(size_t)k * 512 + c], a);
        h1s[c] = fmaxf(a, 0.f);
    }
    __syncthreads();
    for (int c = tid; c < 1024; c += 256) {
        float a = b4b[c];
        for (int k = 0; k < 512; ++k) a = fmaf(h1s[k], w4b[(size_t)k * 1024 + c], a);
        h4[(size_t)g * 1024 + c] = fmaxf(a, 0.f);
    }
}

// ---------------- Head part 2: maxpool(16) -> fc1(relu) -> fc2 -> bn-ish -----------------
__global__ __launch_bounds__(256)
void head2_kernel(const float* __restrict__ h4,
                  const float* __restrict__ fc1w, const float* __restrict__ fc1b,
                  const float* __restrict__ fc2w, const float* __restrict__ fc2b,
                  const float* __restrict__ gamma, const float* __restrict__ beta,
                  float* __restrict__ out)
{
    const int b   = blockIdx.x;
    const int tid = threadIdx.x;
    __shared__ float gm[1024], g1[1024];
    for (int c = tid; c < 1024; c += 256) {
        float m = 0.f;  // h4 is relu'd (>=0)
        for (int p = 0; p < 16; ++p) m = fmaxf(m, h4[((size_t)b * 16 + p) * 1024 + c]);
        gm[c] = m;
    }
    __syncthreads();
    for (int c = tid; c < 1024; c += 256) {
        float a = fc1b[c];
        for (int k = 0; k < 1024; ++k) a = fmaf(gm[k], fc1w[(size_t)k * 1024 + c], a);
        g1[c] = fmaxf(a, 0.f);
    }
    __syncthreads();
    if (tid < 128) {
        const float s = sqrtf(1.00001f);
        int c = tid;
        float a = fc2b[c];
        for (int k = 0; k < 1024; ++k) a = fmaf(g1[k], fc2w[(size_t)k * 128 + c], a);
        out[(size_t)b * 128 + c] = (a / s) * gamma[c] + beta[c];
    }
}

// ---------------------------------------------------------------------------
extern "C" void kernel_launch(void* const* d_in, const int* in_sizes, int n_in,
                              void* d_out, int out_size, void* d_ws, size_t ws_size,
                              hipStream_t stream)
{
    const float* pc   = (const float*)d_in[0];
    const float* w1a  = (const float*)d_in[1];  const float* b1a = (const float*)d_in[2];
    const float* w1b  = (const float*)d_in[3];  const float* b1b = (const float*)d_in[4];
    const float* w2a  = (const float*)d_in[5];  const float* b2a = (const float*)d_in[6];
    const float* w2b  = (const float*)d_in[7];  const float* b2b = (const float*)d_in[8];
    const float* w3a  = (const float*)d_in[9];  const float* b3a = (const float*)d_in[10];
    const float* w3b  = (const float*)d_in[11]; const float* b3b = (const float*)d_in[12];
    const float* w4a  = (const float*)d_in[13]; const float* b4a = (const float*)d_in[14];
    const float* w4b  = (const float*)d_in[15]; const float* b4b = (const float*)d_in[16];
    const float* fc1w = (const float*)d_in[17]; const float* fc1b = (const float*)d_in[18];
    const float* fc2w = (const float*)d_in[19]; const float* fc2b = (const float*)d_in[20];
    const float* gam  = (const float*)d_in[21]; const float* bet  = (const float*)d_in[22];
    float* out = (float*)d_out;

    char* ws = (char*)d_ws;
    size_t off = 0;
    auto alloc = [&](size_t bytes) -> void* {
        void* p = ws + off;
        off = (off + bytes + 255) & ~(size_t)255;
        return p;
    };
    float* nxyz1  = (float*)alloc((size_t)32 * 256 * 3 * 4);
    int*   gidx1  = (int*)  alloc((size_t)32 * 256 * 64 * 4);
    float* feats1 = (float*)alloc((size_t)32 * 256 * 128 * 4);
    float* nxyz2  = (float*)alloc((size_t)32 * 64 * 3 * 4);
    int*   gidx2  = (int*)  alloc((size_t)32 * 64 * 64 * 4);
    float* feats2 = (float*)alloc((size_t)32 * 64 * 256 * 4);
    float* nxyz3  = (float*)alloc((size_t)32 * 16 * 3 * 4);
    int*   gidx3  = (int*)  alloc((size_t)32 * 16 * 32 * 4);
    float* feats3 = (float*)alloc((size_t)32 * 16 * 512 * 4);
    float* h4     = (float*)alloc((size_t)32 * 16 * 1024 * 4);

    // radii squared, matching JAX: python-float64 r*r then cast to f32
    const float r2a = (float)(0.1 * 0.1);
    const float r2b = (float)(0.2 * 0.2);
    const float r2c = (float)(0.4 * 0.4);

    // ---- SA stage 1: N=4096 -> S=256, ns=64, 9 -> 64 -> 128
    fps_kernel<4096, 256, 6, 256><<<32, 256, 0, stream>>>(pc, nxyz1);
    bq_kernel<4096, 64, 6><<<(32 * 256 + 3) / 4, 256, 0, stream>>>(pc, nxyz1, gidx1, r2a, 256, 32 * 256);
    sa_mlp_kernel<64, 9, 64, 128, 128, 4096, 0><<<32 * 256, 128, 0, stream>>>(
        pc, pc, nxyz1, gidx1, w1a, b1a, w1b, b1b, feats1, 256);

    // ---- SA stage 2: N=256 -> S=64, ns=64, 131 -> 128 -> 256
    fps_kernel<256, 64, 3, 256><<<32, 256, 0, stream>>>(nxyz1, nxyz2);
    bq_kernel<256, 64, 3><<<(32 * 64 + 3) / 4, 256, 0, stream>>>(nxyz1, nxyz2, gidx2, r2b, 64, 32 * 64);
    sa_mlp_kernel<64, 131, 128, 256, 128, 256, 1><<<32 * 64, 128, 0, stream>>>(
        nxyz1, feats1, nxyz2, gidx2, w2a, b2a, w2b, b2b, feats2, 64);

    // ---- SA stage 3: N=64 -> S=16, ns=32, 259 -> 256 -> 512
    fps_kernel<64, 16, 3, 256><<<32, 256, 0, stream>>>(nxyz2, nxyz3);
    bq_kernel<64, 32, 3><<<(32 * 16 + 3) / 4, 256, 0, stream>>>(nxyz2, nxyz3, gidx3, r2c, 16, 32 * 16);
    sa_mlp_kernel<32, 259, 256, 512, 128, 64, 1><<<32 * 16, 128, 0, stream>>>(
        nxyz2, feats2, nxyz3, gidx3, w3a, b3a, w3b, b3b, feats3, 16);

    // ---- Head
    head1_kernel<<<32 * 16, 256, 0, stream>>>(nxyz3, feats3, w4a, b4a, w4b, b4b, h4);
    head2_kernel<<<32, 256, 0, stream>>>(h4, fc1w, fc1b, fc2w, fc2b, gam, bet, out);
}

// Round 2
// 1284.825 us; speedup vs baseline: 1.1619x; 1.1619x over previous
//
#include <hip/hip_runtime.h>

#define DEV static __device__ __forceinline__

DEV float sqdist(float dx, float dy, float dz) {
    // ((dx*dx + dy*dy) + dz*dz) with no FMA contraction — must match numpy f32
    return __fadd_rn(__fadd_rn(__fmul_rn(dx, dx), __fmul_rn(dy, dy)), __fmul_rn(dz, dz));
}

DEV void fma4(float4& acc, float h, const float4& w) {
    acc.x = fmaf(h, w.x, acc.x); acc.y = fmaf(h, w.y, acc.y);
    acc.z = fmaf(h, w.z, acc.z); acc.w = fmaf(h, w.w, acc.w);
}

// ---------------- Farthest point sampling -----------------
template<int N, int NPOINT, int STRIDE, int T>
__global__ __launch_bounds__(T)
void fps_kernel(const float* __restrict__ xyz, float* __restrict__ new_xyz)
{
    constexpr int K  = (N + T - 1) / T;
    constexpr int NW = T / 64;
    const int b   = blockIdx.x;
    const int tid = threadIdx.x;
    __shared__ float px[N], py[N], pz[N];
    __shared__ float rv[NW];
    __shared__ int   ri[NW];
    __shared__ int   s_far;

    const float* base = xyz + (size_t)b * N * STRIDE;
    float rx[K], ry[K], rz[K], d[K];
#pragma unroll
    for (int k = 0; k < K; ++k) {
        int p = tid + k * T;
        float x = 0.f, y = 0.f, z = 0.f;
        if (N % T == 0 || p < N) {
            x = base[p * STRIDE + 0];
            y = base[p * STRIDE + 1];
            z = base[p * STRIDE + 2];
            px[p] = x; py[p] = y; pz[p] = z;
        }
        rx[k] = x; ry[k] = y; rz[k] = z;
        d[k] = 1e10f;
    }
    if (tid == 0) s_far = 0;
    __syncthreads();

    int far = 0;
    float* out = new_xyz + (size_t)b * NPOINT * 3;
    for (int s = 0; s < NPOINT; ++s) {
        float cx = px[far], cy = py[far], cz = pz[far];
        if (tid == 0) { out[s * 3 + 0] = cx; out[s * 3 + 1] = cy; out[s * 3 + 2] = cz; }
        float bestv = -1.0f; int besti = 0x7fffffff;
#pragma unroll
        for (int k = 0; k < K; ++k) {
            int p = tid + k * T;
            if (N % T == 0 || p < N) {
                float d2 = sqdist(rx[k] - cx, ry[k] - cy, rz[k] - cz);
                d[k] = fminf(d[k], d2);
                if (d[k] > bestv) { bestv = d[k]; besti = p; }
            }
        }
#pragma unroll
        for (int off = 1; off < 64; off <<= 1) {
            float ov = __shfl_xor(bestv, off);
            int   oi = __shfl_xor(besti, off);
            if (ov > bestv || (ov == bestv && oi < besti)) { bestv = ov; besti = oi; }
        }
        if ((tid & 63) == 0) { rv[tid >> 6] = bestv; ri[tid >> 6] = besti; }
        __syncthreads();
        if (tid == 0) {
            float bv = rv[0]; int bi = ri[0];
#pragma unroll
            for (int w = 1; w < NW; ++w)
                if (rv[w] > bv || (rv[w] == bv && ri[w] < bi)) { bv = rv[w]; bi = ri[w]; }
            s_far = bi;
        }
        __syncthreads();
        far = s_far;
    }
}

// ---------------- Ball query -----------------
template<int N, int NSAMP, int STRIDE>
__global__ __launch_bounds__(256)
void bq_kernel(const float* __restrict__ xyz, const float* __restrict__ newxyz,
               int* __restrict__ gidx, float r2, int S, int total)
{
    const int wid = blockIdx.x * 4 + (threadIdx.x >> 6);
    if (wid >= total) return;
    const int lane = threadIdx.x & 63;
    const int b = wid / S;
    const float cx = newxyz[(size_t)wid * 3 + 0];
    const float cy = newxyz[(size_t)wid * 3 + 1];
    const float cz = newxyz[(size_t)wid * 3 + 2];
    const float* base = xyz + (size_t)b * N * STRIDE;
    int* out = gidx + (size_t)wid * NSAMP;

    int count = 0, first = N - 1;
    constexpr int NCH = (N + 63) / 64;
    for (int ch = 0; ch < NCH; ++ch) {
        int p = ch * 64 + lane;
        bool pred = false;
        if (N % 64 == 0 || p < N) {
            float dx = base[p * STRIDE + 0] - cx;
            float dy = base[p * STRIDE + 1] - cy;
            float dz = base[p * STRIDE + 2] - cz;
            pred = sqdist(dx, dy, dz) < r2;
        }
        unsigned long long m = __ballot(pred);
        if (m) {
            if (count == 0) first = ch * 64 + __builtin_ctzll(m);
            int pos = count + __popcll(m & ((1ull << lane) - 1ull));
            if (pred && pos < NSAMP) out[pos] = p;
            count += __popcll(m);
            if (count >= NSAMP) break;
        }
    }
    if (count > NSAMP) count = NSAMP;
    for (int pos = count + lane; pos < NSAMP; pos += 64) out[pos] = first;
}

// ---------------- Grouped 2-layer MLP + maxpool, v2 -----------------
// One block per group, T=256. K-chunked gather (xgc small) with layer-1
// partial sums in registers (TPT tiles/thread, statically unrolled).
// MODE 0: stage1 (xyz stride 6, feats = pc permuted). MODE 1: feats array.
// MODE 2: head (no gather indices, no centroid subtraction).
template<int NS, int CIN, int C1, int C2, int NSRC, int MODE>
__global__ __launch_bounds__(256)
void sa_mlp2_kernel(const float* __restrict__ sxyz, const float* __restrict__ sfeat,
                    const float* __restrict__ newxyz, const int* __restrict__ gidx,
                    const float* __restrict__ W1, const float* __restrict__ B1v,
                    const float* __restrict__ W2, const float* __restrict__ B2v,
                    float* __restrict__ outf, int S)
{
    constexpr int T    = 256;
    constexpr int KCC  = (CIN < 32) ? CIN : 32;            // k-chunk length
    constexpr int KCP0 = ((KCC + 3) / 4) * 4 + 4;
    constexpr int KCP  = ((KCP0 / 4) % 2 == 0) ? KCP0 + 4 : KCP0;  // odd quad stride
    constexpr int NPT  = NS / 4;
    constexpr int NCT1 = C1 / 4;
    constexpr int TPT  = (NPT * NCT1) / T;                 // phase-A tiles per thread
    constexpr int C1P  = C1 + 4;
    constexpr int CT2  = C2 / 4;
    constexpr int PB   = T / CT2;                          // phase-B parallel point-blocks
    constexpr int JP   = NPT / PB;                         // phase-B ptiles per thread
    constexpr int XS   = (MODE == 0) ? 6 : 3;
    constexpr int CF   = CIN - 3;
    static_assert(NS % 4 == 0 && C1 % 4 == 0 && C2 % 4 == 0, "");
    static_assert((NPT * NCT1) % T == 0 && TPT >= 1, "");
    static_assert(T % CT2 == 0 && NPT % PB == 0, "");

    __shared__ float xgc[NS][KCP];
    __shared__ __align__(16) float h1s[NS][C1P];
    __shared__ int   gix[NS];
    __shared__ float ctr[3];
    __shared__ float mpart[(PB > 1) ? PB * C2 : 4];

    const int g   = blockIdx.x;
    const int b   = g / S;
    const int tid = threadIdx.x;

    if constexpr (MODE != 2) {
        if (tid < 3) ctr[tid] = newxyz[(size_t)g * 3 + tid];
        for (int i = tid; i < NS; i += T) gix[i] = gidx[(size_t)g * NS + i];
    }
    __syncthreads();

    // ---- Phase A: layer 1, K-chunked, accumulators in registers ----
    float4 acc[TPT][4];
#pragma unroll
    for (int j = 0; j < TPT; ++j) {
        const int tl = tid + j * T;
        const int ct = tl % NCT1;
        const float4 bb = *(const float4*)&B1v[ct * 4];
#pragma unroll
        for (int i = 0; i < 4; ++i) acc[j][i] = bb;
    }

    const int nchunk = (CIN + KCC - 1) / KCC;
    for (int cch = 0; cch < nchunk; ++cch) {
        const int k0 = cch * KCC;
        const int kcLen = (CIN - k0 < KCC) ? (CIN - k0) : KCC;
        if (cch > 0) __syncthreads();
        // gather chunk
        for (int idx = tid; idx < NS * kcLen; idx += T) {
            const int p = idx / kcLen, kk = idx - p * kcLen, k = k0 + kk;
            float v;
            if constexpr (MODE == 2) {
                v = (k < 3) ? sxyz[((size_t)g * NS + p) * 3 + k]
                            : sfeat[((size_t)g * NS + p) * CF + (k - 3)];
            } else {
                const int gi = gix[p];
                if (k < 3) {
                    v = sxyz[((size_t)b * NSRC + gi) * XS + k] - ctr[k];
                } else if constexpr (MODE == 0) {
                    const int j2 = k - 3;
                    v = sfeat[((size_t)b * NSRC + gi) * 6 + (j2 < 3 ? 3 + j2 : j2 - 3)];
                } else {
                    v = sfeat[((size_t)b * NSRC + gi) * CF + (k - 3)];
                }
            }
            xgc[p][kk] = v;
        }
        __syncthreads();
        // compute chunk
#pragma unroll
        for (int j = 0; j < TPT; ++j) {
            const int tl = tid + j * T;
            const int pt = tl / NCT1, ct = tl % NCT1;
            const int p0 = pt * 4, c0 = ct * 4;
            int kk = 0;
            for (; kk + 4 <= kcLen; kk += 4) {
                const float4 xa = *(const float4*)&xgc[p0 + 0][kk];
                const float4 xb = *(const float4*)&xgc[p0 + 1][kk];
                const float4 xc = *(const float4*)&xgc[p0 + 2][kk];
                const float4 xd = *(const float4*)&xgc[p0 + 3][kk];
                const float4 w0 = *(const float4*)&W1[(size_t)(k0 + kk + 0) * C1 + c0];
                const float4 w1 = *(const float4*)&W1[(size_t)(k0 + kk + 1) * C1 + c0];
                const float4 w2 = *(const float4*)&W1[(size_t)(k0 + kk + 2) * C1 + c0];
                const float4 w3 = *(const float4*)&W1[(size_t)(k0 + kk + 3) * C1 + c0];
                fma4(acc[j][0], xa.x, w0); fma4(acc[j][0], xa.y, w1); fma4(acc[j][0], xa.z, w2); fma4(acc[j][0], xa.w, w3);
                fma4(acc[j][1], xb.x, w0); fma4(acc[j][1], xb.y, w1); fma4(acc[j][1], xb.z, w2); fma4(acc[j][1], xb.w, w3);
                fma4(acc[j][2], xc.x, w0); fma4(acc[j][2], xc.y, w1); fma4(acc[j][2], xc.z, w2); fma4(acc[j][2], xc.w, w3);
                fma4(acc[j][3], xd.x, w0); fma4(acc[j][3], xd.y, w1); fma4(acc[j][3], xd.z, w2); fma4(acc[j][3], xd.w, w3);
            }
            for (; kk < kcLen; ++kk) {
                const float4 w = *(const float4*)&W1[(size_t)(k0 + kk) * C1 + c0];
                fma4(acc[j][0], xgc[p0 + 0][kk], w);
                fma4(acc[j][1], xgc[p0 + 1][kk], w);
                fma4(acc[j][2], xgc[p0 + 2][kk], w);
                fma4(acc[j][3], xgc[p0 + 3][kk], w);
            }
        }
    }
    // write h1 (relu)
    __syncthreads();
#pragma unroll
    for (int j = 0; j < TPT; ++j) {
        const int tl = tid + j * T;
        const int pt = tl / NCT1, ct = tl % NCT1;
        const int p0 = pt * 4, c0 = ct * 4;
#pragma unroll
        for (int i = 0; i < 4; ++i) {
            float4 r;
            r.x = fmaxf(acc[j][i].x, 0.f); r.y = fmaxf(acc[j][i].y, 0.f);
            r.z = fmaxf(acc[j][i].z, 0.f); r.w = fmaxf(acc[j][i].w, 0.f);
            *(float4*)&h1s[p0 + i][c0] = r;
        }
    }
    __syncthreads();

    // ---- Phase B: layer 2 + maxpool ----
    {
        const int ct = tid % CT2, pb = tid / CT2;
        const int c0 = ct * 4;
        const float4 bb = *(const float4*)&B2v[c0];
        float4 m; m.x = 0.f; m.y = 0.f; m.z = 0.f; m.w = 0.f;  // relu>=0
#pragma unroll
        for (int jp = 0; jp < JP; ++jp) {
            const int p0 = (pb + jp * PB) * 4;
            float4 a0 = bb, a1 = bb, a2 = bb, a3 = bb;
            for (int k = 0; k < C1; k += 4) {
                const float4 hA = *(const float4*)&h1s[p0 + 0][k];
                const float4 hB = *(const float4*)&h1s[p0 + 1][k];
                const float4 hC = *(const float4*)&h1s[p0 + 2][k];
                const float4 hD = *(const float4*)&h1s[p0 + 3][k];
                const float4 w0 = *(const float4*)&W2[(size_t)(k + 0) * C2 + c0];
                const float4 w1 = *(const float4*)&W2[(size_t)(k + 1) * C2 + c0];
                const float4 w2 = *(const float4*)&W2[(size_t)(k + 2) * C2 + c0];
                const float4 w3 = *(const float4*)&W2[(size_t)(k + 3) * C2 + c0];
                fma4(a0, hA.x, w0); fma4(a0, hA.y, w1); fma4(a0, hA.z, w2); fma4(a0, hA.w, w3);
                fma4(a1, hB.x, w0); fma4(a1, hB.y, w1); fma4(a1, hB.z, w2); fma4(a1, hB.w, w3);
                fma4(a2, hC.x, w0); fma4(a2, hC.y, w1); fma4(a2, hC.z, w2); fma4(a2, hC.w, w3);
                fma4(a3, hD.x, w0); fma4(a3, hD.y, w1); fma4(a3, hD.z, w2); fma4(a3, hD.w, w3);
            }
            m.x = fmaxf(m.x, fmaxf(fmaxf(a0.x, a1.x), fmaxf(a2.x, a3.x)));
            m.y = fmaxf(m.y, fmaxf(fmaxf(a0.y, a1.y), fmaxf(a2.y, a3.y)));
            m.z = fmaxf(m.z, fmaxf(fmaxf(a0.z, a1.z), fmaxf(a2.z, a3.z)));
            m.w = fmaxf(m.w, fmaxf(fmaxf(a0.w, a1.w), fmaxf(a2.w, a3.w)));
        }
        if constexpr (PB == 1) {
            *(float4*)&outf[(size_t)g * C2 + c0] = m;
        } else {
            *(float4*)&mpart[pb * C2 + c0] = m;
            __syncthreads();
            for (int c = tid; c < C2; c += T) {
                float mm = mpart[c];
#pragma unroll
                for (int q = 1; q < PB; ++q) mm = fmaxf(mm, mpart[q * C2 + c]);
                outf[(size_t)g * C2 + c] = mm;
            }
        }
    }
}

// ---------------- Head part 2: fc1(relu) -> fc2 -> bn-ish -----------------
__global__ __launch_bounds__(256)
void head2_kernel(const float* __restrict__ g4,
                  const float* __restrict__ fc1w, const float* __restrict__ fc1b,
                  const float* __restrict__ fc2w, const float* __restrict__ fc2b,
                  const float* __restrict__ gamma, const float* __restrict__ beta,
                  float* __restrict__ out)
{
    const int b   = blockIdx.x;
    const int tid = threadIdx.x;
    __shared__ float gm[1024], g1[1024];
    for (int c = tid; c < 1024; c += 256) gm[c] = g4[(size_t)b * 1024 + c];
    __syncthreads();
    {
        const int c0 = tid * 4;
        float4 a = *(const float4*)&fc1b[c0];
#pragma unroll 4
        for (int k = 0; k < 1024; ++k) {
            const float4 w = *(const float4*)&fc1w[(size_t)k * 1024 + c0];
            fma4(a, gm[k], w);
        }
        g1[c0 + 0] = fmaxf(a.x, 0.f); g1[c0 + 1] = fmaxf(a.y, 0.f);
        g1[c0 + 2] = fmaxf(a.z, 0.f); g1[c0 + 3] = fmaxf(a.w, 0.f);
    }
    __syncthreads();
    if (tid < 128) {
        const float s = sqrtf(1.00001f);
        const int c = tid;
        float a = fc2b[c];
#pragma unroll 4
        for (int k = 0; k < 1024; ++k) a = fmaf(g1[k], fc2w[(size_t)k * 128 + c], a);
        out[(size_t)b * 128 + c] = (a / s) * gamma[c] + beta[c];
    }
}

// ---------------------------------------------------------------------------
extern "C" void kernel_launch(void* const* d_in, const int* in_sizes, int n_in,
                              void* d_out, int out_size, void* d_ws, size_t ws_size,
                              hipStream_t stream)
{
    const float* pc   = (const float*)d_in[0];
    const float* w1a  = (const float*)d_in[1];  const float* b1a = (const float*)d_in[2];
    const float* w1b  = (const float*)d_in[3];  const float* b1b = (const float*)d_in[4];
    const float* w2a  = (const float*)d_in[5];  const float* b2a = (const float*)d_in[6];
    const float* w2b  = (const float*)d_in[7];  const float* b2b = (const float*)d_in[8];
    const float* w3a  = (const float*)d_in[9];  const float* b3a = (const float*)d_in[10];
    const float* w3b  = (const float*)d_in[11]; const float* b3b = (const float*)d_in[12];
    const float* w4a  = (const float*)d_in[13]; const float* b4a = (const float*)d_in[14];
    const float* w4b  = (const float*)d_in[15]; const float* b4b = (const float*)d_in[16];
    const float* fc1w = (const float*)d_in[17]; const float* fc1b = (const float*)d_in[18];
    const float* fc2w = (const float*)d_in[19]; const float* fc2b = (const float*)d_in[20];
    const float* gam  = (const float*)d_in[21]; const float* bet  = (const float*)d_in[22];
    float* out = (float*)d_out;

    char* ws = (char*)d_ws;
    size_t off = 0;
    auto alloc = [&](size_t bytes) -> void* {
        void* p = ws + off;
        off = (off + bytes + 255) & ~(size_t)255;
        return p;
    };
    float* nxyz1  = (float*)alloc((size_t)32 * 256 * 3 * 4);
    int*   gidx1  = (int*)  alloc((size_t)32 * 256 * 64 * 4);
    float* feats1 = (float*)alloc((size_t)32 * 256 * 128 * 4);
    float* nxyz2  = (float*)alloc((size_t)32 * 64 * 3 * 4);
    int*   gidx2  = (int*)  alloc((size_t)32 * 64 * 64 * 4);
    float* feats2 = (float*)alloc((size_t)32 * 64 * 256 * 4);
    float* nxyz3  = (float*)alloc((size_t)32 * 16 * 3 * 4);
    int*   gidx3  = (int*)  alloc((size_t)32 * 16 * 32 * 4);
    float* feats3 = (float*)alloc((size_t)32 * 16 * 512 * 4);
    float* g4     = (float*)alloc((size_t)32 * 1024 * 4);

    const float r2a = (float)(0.1 * 0.1);
    const float r2b = (float)(0.2 * 0.2);
    const float r2c = (float)(0.4 * 0.4);

    // ---- SA stage 1: N=4096 -> S=256, ns=64, 9 -> 64 -> 128
    fps_kernel<4096, 256, 6, 512><<<32, 512, 0, stream>>>(pc, nxyz1);
    bq_kernel<4096, 64, 6><<<(32 * 256 + 3) / 4, 256, 0, stream>>>(pc, nxyz1, gidx1, r2a, 256, 32 * 256);
    sa_mlp2_kernel<64, 9, 64, 128, 4096, 0><<<32 * 256, 256, 0, stream>>>(
        pc, pc, nxyz1, gidx1, w1a, b1a, w1b, b1b, feats1, 256);

    // ---- SA stage 2: N=256 -> S=64, ns=64, 131 -> 128 -> 256
    fps_kernel<256, 64, 3, 256><<<32, 256, 0, stream>>>(nxyz1, nxyz2);
    bq_kernel<256, 64, 3><<<(32 * 64 + 3) / 4, 256, 0, stream>>>(nxyz1, nxyz2, gidx2, r2b, 64, 32 * 64);
    sa_mlp2_kernel<64, 131, 128, 256, 256, 1><<<32 * 64, 256, 0, stream>>>(
        nxyz1, feats1, nxyz2, gidx2, w2a, b2a, w2b, b2b, feats2, 64);

    // ---- SA stage 3: N=64 -> S=16, ns=32, 259 -> 256 -> 512
    fps_kernel<64, 16, 3, 256><<<32, 256, 0, stream>>>(nxyz2, nxyz3);
    bq_kernel<64, 32, 3><<<(32 * 16 + 3) / 4, 256, 0, stream>>>(nxyz2, nxyz3, gidx3, r2c, 16, 32 * 16);
    sa_mlp2_kernel<32, 259, 256, 512, 64, 1><<<32 * 16, 256, 0, stream>>>(
        nxyz2, feats2, nxyz3, gidx3, w3a, b3a, w3b, b3b, feats3, 16);

    // ---- Head: per-batch 16-point MLP 515->512->1024 + maxpool(16)
    sa_mlp2_kernel<16, 515, 512, 1024, 16, 2><<<32, 256, 0, stream>>>(
        nxyz3, feats3, nullptr, nullptr, w4a, b4a, w4b, b4b, g4, 1);
    head2_kernel<<<32, 256, 0, stream>>>(g4, fc1w, fc1b, fc2w, fc2b, gam, bet, out);
}

// Round 4
// 1143.018 us; speedup vs baseline: 1.3061x; 1.1241x over previous
//
#include <hip/hip_runtime.h>

#define DEV static __device__ __forceinline__

DEV float sqdist(float dx, float dy, float dz) {
    // ((dx*dx + dy*dy) + dz*dz) with no FMA contraction — must match numpy f32
    return __fadd_rn(__fadd_rn(__fmul_rn(dx, dx), __fmul_rn(dy, dy)), __fmul_rn(dz, dz));
}

DEV void fma4(float4& acc, float h, const float4& w) {
    acc.x = fmaf(h, w.x, acc.x); acc.y = fmaf(h, w.y, acc.y);
    acc.z = fmaf(h, w.z, acc.z); acc.w = fmaf(h, w.w, acc.w);
}

// ---- argmax combine steps (value desc, index asc on ties) ----
template<int CTRL>
DEV int dpp_mov(int v) {
    return __builtin_amdgcn_update_dpp(v, v, CTRL, 0xF, 0xF, false);
}
template<int CTRL>
DEV void red_step_dpp(float& bv, int& bi) {
    float ov = __builtin_bit_cast(float, dpp_mov<CTRL>(__builtin_bit_cast(int, bv)));
    int   oi = dpp_mov<CTRL>(bi);
    if (ov > bv || (ov == bv && oi < bi)) { bv = ov; bi = oi; }
}
DEV void red_step_shfl(float& bv, int& bi, int mask) {
    float ov = __shfl_xor(bv, mask);
    int   oi = __shfl_xor(bi, mask);
    if (ov > bv || (ov == bv && oi < bi)) { bv = ov; bi = oi; }
}

// ---------------- Farthest point sampling, latency-optimized -----------------
// One block per batch. Coords in registers + LDS copy for centroid broadcast.
// Per step: DPP+shfl wave argmax, ONE barrier, ping-pong LDS slots, redundant
// cross-wave reduce in all threads (no tid0 serialization, no s_far bounce).
template<int N, int NPOINT, int STRIDE, int T>
__global__ __launch_bounds__(T)
void fps_kernel(const float* __restrict__ xyz, float* __restrict__ new_xyz)
{
    constexpr int K  = (N + T - 1) / T;
    constexpr int NW = T / 64;
    const int b   = blockIdx.x;
    const int tid = threadIdx.x;
    __shared__ float px[N], py[N], pz[N];
    __shared__ float rv[2][(NW > 1) ? NW : 1];
    __shared__ int   ri[2][(NW > 1) ? NW : 1];

    const float* base = xyz + (size_t)b * N * STRIDE;
    float rx[K], ry[K], rz[K], d[K];
#pragma unroll
    for (int k = 0; k < K; ++k) {
        int p = tid + k * T;
        float x = 0.f, y = 0.f, z = 0.f;
        if (N % T == 0 || p < N) {
            x = base[p * STRIDE + 0];
            y = base[p * STRIDE + 1];
            z = base[p * STRIDE + 2];
            px[p] = x; py[p] = y; pz[p] = z;
        }
        rx[k] = x; ry[k] = y; rz[k] = z;
        d[k] = 1e10f;
    }
    __syncthreads();

    float cx = px[0], cy = py[0], cz = pz[0];
    float* out = new_xyz + (size_t)b * NPOINT * 3;
    for (int s = 0; s < NPOINT; ++s) {
        if (tid == 0) { out[s * 3 + 0] = cx; out[s * 3 + 1] = cy; out[s * 3 + 2] = cz; }
        float bestv = -1.0f; int besti = 0x7fffffff;
#pragma unroll
        for (int k = 0; k < K; ++k) {
            int p = tid + k * T;
            if (N % T == 0 || p < N) {
                float d2 = sqdist(rx[k] - cx, ry[k] - cy, rz[k] - cz);
                d[k] = fminf(d[k], d2);
                if (d[k] > bestv) { bestv = d[k]; besti = p; }  // k asc => lowest p on tie
            }
        }
        // wave all-reduce argmax: DPP within 16 lanes, shfl for 16/32
        red_step_dpp<0xB1>(bestv, besti);    // quad_perm: xor 1
        red_step_dpp<0x4E>(bestv, besti);    // quad_perm: xor 2
        red_step_dpp<0x141>(bestv, besti);   // row_half_mirror (xor 4 within row)
        red_step_dpp<0x140>(bestv, besti);   // row_mirror (xor 8 within row)
        red_step_shfl(bestv, besti, 16);
        red_step_shfl(bestv, besti, 32);

        int far;
        if constexpr (NW > 1) {
            const int sl = s & 1;
            if ((tid & 63) == 0) { rv[sl][tid >> 6] = bestv; ri[sl][tid >> 6] = besti; }
            __syncthreads();
            float bvv = rv[sl][0]; int bii = ri[sl][0];
#pragma unroll
            for (int q = 1; q < NW; ++q) {
                float qv = rv[sl][q]; int qi = ri[sl][q];
                if (qv > bvv || (qv == bvv && qi < bii)) { bvv = qv; bii = qi; }
            }
            far = bii;
        } else {
            far = besti;
        }
        cx = px[far]; cy = py[far]; cz = pz[far];
    }
}

// ---------------- Ball query -----------------
template<int N, int NSAMP, int STRIDE>
__global__ __launch_bounds__(256)
void bq_kernel(const float* __restrict__ xyz, const float* __restrict__ newxyz,
               int* __restrict__ gidx, float r2, int S, int total)
{
    const int wid = blockIdx.x * 4 + (threadIdx.x >> 6);
    if (wid >= total) return;
    const int lane = threadIdx.x & 63;
    const int b = wid / S;
    const float cx = newxyz[(size_t)wid * 3 + 0];
    const float cy = newxyz[(size_t)wid * 3 + 1];
    const float cz = newxyz[(size_t)wid * 3 + 2];
    const float* base = xyz + (size_t)b * N * STRIDE;
    int* out = gidx + (size_t)wid * NSAMP;

    int count = 0, first = N - 1;
    constexpr int NCH = (N + 63) / 64;
    for (int ch = 0; ch < NCH; ++ch) {
        int p = ch * 64 + lane;
        bool pred = false;
        if (N % 64 == 0 || p < N) {
            float dx = base[p * STRIDE + 0] - cx;
            float dy = base[p * STRIDE + 1] - cy;
            float dz = base[p * STRIDE + 2] - cz;
            pred = sqdist(dx, dy, dz) < r2;
        }
        unsigned long long m = __ballot(pred);
        if (m) {
            if (count == 0) first = ch * 64 + __builtin_ctzll(m);
            int pos = count + __popcll(m & ((1ull << lane) - 1ull));
            if (pred && pos < NSAMP) out[pos] = p;
            count += __popcll(m);
            if (count >= NSAMP) break;
        }
    }
    if (count > NSAMP) count = NSAMP;
    for (int pos = count + lane; pos < NSAMP; pos += 64) out[pos] = first;
}

// ---------------- Grouped 2-layer MLP + maxpool, v2 -----------------
// MODE 0: stage1 (xyz stride 6, feats = pc permuted). MODE 1: feats array.
// MODE 2: head (no gather indices, no centroid subtraction).
template<int NS, int CIN, int C1, int C2, int NSRC, int MODE>
__global__ __launch_bounds__(256)
void sa_mlp2_kernel(const float* __restrict__ sxyz, const float* __restrict__ sfeat,
                    const float* __restrict__ newxyz, const int* __restrict__ gidx,
                    const float* __restrict__ W1, const float* __restrict__ B1v,
                    const float* __restrict__ W2, const float* __restrict__ B2v,
                    float* __restrict__ outf, int S)
{
    constexpr int T    = 256;
    constexpr int KCC  = (CIN < 32) ? CIN : 32;            // k-chunk length
    constexpr int KCP0 = ((KCC + 3) / 4) * 4 + 4;
    constexpr int KCP  = ((KCP0 / 4) % 2 == 0) ? KCP0 + 4 : KCP0;  // odd quad stride
    constexpr int NPT  = NS / 4;
    constexpr int NCT1 = C1 / 4;
    constexpr int TPT  = (NPT * NCT1) / T;                 // phase-A tiles per thread
    constexpr int C1P  = C1 + 4;
    constexpr int CT2  = C2 / 4;
    constexpr int PB   = T / CT2;                          // phase-B parallel point-blocks
    constexpr int JP   = NPT / PB;                         // phase-B ptiles per thread
    constexpr int XS   = (MODE == 0) ? 6 : 3;
    constexpr int CF   = CIN - 3;
    static_assert(NS % 4 == 0 && C1 % 4 == 0 && C2 % 4 == 0, "");
    static_assert((NPT * NCT1) % T == 0 && TPT >= 1, "");
    static_assert(T % CT2 == 0 && NPT % PB == 0, "");

    __shared__ float xgc[NS][KCP];
    __shared__ __align__(16) float h1s[NS][C1P];
    __shared__ int   gix[NS];
    __shared__ float ctr[3];
    __shared__ float mpart[(PB > 1) ? PB * C2 : 4];

    const int g   = blockIdx.x;
    const int b   = g / S;
    const int tid = threadIdx.x;

    if constexpr (MODE != 2) {
        if (tid < 3) ctr[tid] = newxyz[(size_t)g * 3 + tid];
        for (int i = tid; i < NS; i += T) gix[i] = gidx[(size_t)g * NS + i];
    }
    __syncthreads();

    // ---- Phase A: layer 1, K-chunked, accumulators in registers ----
    float4 acc[TPT][4];
#pragma unroll
    for (int j = 0; j < TPT; ++j) {
        const int tl = tid + j * T;
        const int ct = tl % NCT1;
        const float4 bb = *(const float4*)&B1v[ct * 4];
#pragma unroll
        for (int i = 0; i < 4; ++i) acc[j][i] = bb;
    }

    const int nchunk = (CIN + KCC - 1) / KCC;
    for (int cch = 0; cch < nchunk; ++cch) {
        const int k0 = cch * KCC;
        const int kcLen = (CIN - k0 < KCC) ? (CIN - k0) : KCC;
        if (cch > 0) __syncthreads();
        // gather chunk
        for (int idx = tid; idx < NS * kcLen; idx += T) {
            const int p = idx / kcLen, kk = idx - p * kcLen, k = k0 + kk;
            float v;
            if constexpr (MODE == 2) {
                v = (k < 3) ? sxyz[((size_t)g * NS + p) * 3 + k]
                            : sfeat[((size_t)g * NS + p) * CF + (k - 3)];
            } else {
                const int gi = gix[p];
                if (k < 3) {
                    v = sxyz[((size_t)b * NSRC + gi) * XS + k] - ctr[k];
                } else if constexpr (MODE == 0) {
                    const int j2 = k - 3;
                    v = sfeat[((size_t)b * NSRC + gi) * 6 + (j2 < 3 ? 3 + j2 : j2 - 3)];
                } else {
                    v = sfeat[((size_t)b * NSRC + gi) * CF + (k - 3)];
                }
            }
            xgc[p][kk] = v;
        }
        __syncthreads();
        // compute chunk
#pragma unroll
        for (int j = 0; j < TPT; ++j) {
            const int tl = tid + j * T;
            const int pt = tl / NCT1, ct = tl % NCT1;
            const int p0 = pt * 4, c0 = ct * 4;
            int kk = 0;
            for (; kk + 4 <= kcLen; kk += 4) {
                const float4 xa = *(const float4*)&xgc[p0 + 0][kk];
                const float4 xb = *(const float4*)&xgc[p0 + 1][kk];
                const float4 xc = *(const float4*)&xgc[p0 + 2][kk];
                const float4 xd = *(const float4*)&xgc[p0 + 3][kk];
                const float4 w0 = *(const float4*)&W1[(size_t)(k0 + kk + 0) * C1 + c0];
                const float4 w1 = *(const float4*)&W1[(size_t)(k0 + kk + 1) * C1 + c0];
                const float4 w2 = *(const float4*)&W1[(size_t)(k0 + kk + 2) * C1 + c0];
                const float4 w3 = *(const float4*)&W1[(size_t)(k0 + kk + 3) * C1 + c0];
                fma4(acc[j][0], xa.x, w0); fma4(acc[j][0], xa.y, w1); fma4(acc[j][0], xa.z, w2); fma4(acc[j][0], xa.w, w3);
                fma4(acc[j][1], xb.x, w0); fma4(acc[j][1], xb.y, w1); fma4(acc[j][1], xb.z, w2); fma4(acc[j][1], xb.w, w3);
                fma4(acc[j][2], xc.x, w0); fma4(acc[j][2], xc.y, w1); fma4(acc[j][2], xc.z, w2); fma4(acc[j][2], xc.w, w3);
                fma4(acc[j][3], xd.x, w0); fma4(acc[j][3], xd.y, w1); fma4(acc[j][3], xd.z, w2); fma4(acc[j][3], xd.w, w3);
            }
            for (; kk < kcLen; ++kk) {
                const float4 w = *(const float4*)&W1[(size_t)(k0 + kk) * C1 + c0];
                fma4(acc[j][0], xgc[p0 + 0][kk], w);
                fma4(acc[j][1], xgc[p0 + 1][kk], w);
                fma4(acc[j][2], xgc[p0 + 2][kk], w);
                fma4(acc[j][3], xgc[p0 + 3][kk], w);
            }
        }
    }
    // write h1 (relu)
    __syncthreads();
#pragma unroll
    for (int j = 0; j < TPT; ++j) {
        const int tl = tid + j * T;
        const int pt = tl / NCT1, ct = tl % NCT1;
        const int p0 = pt * 4, c0 = ct * 4;
#pragma unroll
        for (int i = 0; i < 4; ++i) {
            float4 r;
            r.x = fmaxf(acc[j][i].x, 0.f); r.y = fmaxf(acc[j][i].y, 0.f);
            r.z = fmaxf(acc[j][i].z, 0.f); r.w = fmaxf(acc[j][i].w, 0.f);
            *(float4*)&h1s[p0 + i][c0] = r;
        }
    }
    __syncthreads();

    // ---- Phase B: layer 2 + maxpool ----
    {
        const int ct = tid % CT2, pb = tid / CT2;
        const int c0 = ct * 4;
        const float4 bb = *(const float4*)&B2v[c0];
        float4 m; m.x = 0.f; m.y = 0.f; m.z = 0.f; m.w = 0.f;  // relu>=0
#pragma unroll
        for (int jp = 0; jp < JP; ++jp) {
            const int p0 = (pb + jp * PB) * 4;
            float4 a0 = bb, a1 = bb, a2 = bb, a3 = bb;
            for (int k = 0; k < C1; k += 4) {
                const float4 hA = *(const float4*)&h1s[p0 + 0][k];
                const float4 hB = *(const float4*)&h1s[p0 + 1][k];
                const float4 hC = *(const float4*)&h1s[p0 + 2][k];
                const float4 hD = *(const float4*)&h1s[p0 + 3][k];
                const float4 w0 = *(const float4*)&W2[(size_t)(k + 0) * C2 + c0];
                const float4 w1 = *(const float4*)&W2[(size_t)(k + 1) * C2 + c0];
                const float4 w2 = *(const float4*)&W2[(size_t)(k + 2) * C2 + c0];
                const float4 w3 = *(const float4*)&W2[(size_t)(k + 3) * C2 + c0];
                fma4(a0, hA.x, w0); fma4(a0, hA.y, w1); fma4(a0, hA.z, w2); fma4(a0, hA.w, w3);
                fma4(a1, hB.x, w0); fma4(a1, hB.y, w1); fma4(a1, hB.z, w2); fma4(a1, hB.w, w3);
                fma4(a2, hC.x, w0); fma4(a2, hC.y, w1); fma4(a2, hC.z, w2); fma4(a2, hC.w, w3);
                fma4(a3, hD.x, w0); fma4(a3, hD.y, w1); fma4(a3, hD.z, w2); fma4(a3, hD.w, w3);
            }
            m.x = fmaxf(m.x, fmaxf(fmaxf(a0.x, a1.x), fmaxf(a2.x, a3.x)));
            m.y = fmaxf(m.y, fmaxf(fmaxf(a0.y, a1.y), fmaxf(a2.y, a3.y)));
            m.z = fmaxf(m.z, fmaxf(fmaxf(a0.z, a1.z), fmaxf(a2.z, a3.z)));
            m.w = fmaxf(m.w, fmaxf(fmaxf(a0.w, a1.w), fmaxf(a2.w, a3.w)));
        }
        if constexpr (PB == 1) {
            *(float4*)&outf[(size_t)g * C2 + c0] = m;
        } else {
            *(float4*)&mpart[pb * C2 + c0] = m;
            __syncthreads();
            for (int c = tid; c < C2; c += T) {
                float mm = mpart[c];
#pragma unroll
                for (int q = 1; q < PB; ++q) mm = fmaxf(mm, mpart[q * C2 + c]);
                outf[(size_t)g * C2 + c] = mm;
            }
        }
    }
}

// ---------------- Head part 2: fc1(relu) -> fc2 -> bn-ish -----------------
__global__ __launch_bounds__(256)
void head2_kernel(const float* __restrict__ g4,
                  const float* __restrict__ fc1w, const float* __restrict__ fc1b,
                  const float* __restrict__ fc2w, const float* __restrict__ fc2b,
                  const float* __restrict__ gamma, const float* __restrict__ beta,
                  float* __restrict__ out)
{
    const int b   = blockIdx.x;
    const int tid = threadIdx.x;
    __shared__ float gm[1024], g1[1024];
    for (int c = tid; c < 1024; c += 256) gm[c] = g4[(size_t)b * 1024 + c];
    __syncthreads();
    {
        const int c0 = tid * 4;
        float4 a = *(const float4*)&fc1b[c0];
#pragma unroll 4
        for (int k = 0; k < 1024; ++k) {
            const float4 w = *(const float4*)&fc1w[(size_t)k * 1024 + c0];
            fma4(a, gm[k], w);
        }
        g1[c0 + 0] = fmaxf(a.x, 0.f); g1[c0 + 1] = fmaxf(a.y, 0.f);
        g1[c0 + 2] = fmaxf(a.z, 0.f); g1[c0 + 3] = fmaxf(a.w, 0.f);
    }
    __syncthreads();
    if (tid < 128) {
        const float s = sqrtf(1.00001f);
        const int c = tid;
        float a = fc2b[c];
#pragma unroll 4
        for (int k = 0; k < 1024; ++k) a = fmaf(g1[k], fc2w[(size_t)k * 128 + c], a);
        out[(size_t)b * 128 + c] = (a / s) * gamma[c] + beta[c];
    }
}

// ---------------------------------------------------------------------------
extern "C" void kernel_launch(void* const* d_in, const int* in_sizes, int n_in,
                              void* d_out, int out_size, void* d_ws, size_t ws_size,
                              hipStream_t stream)
{
    const float* pc   = (const float*)d_in[0];
    const float* w1a  = (const float*)d_in[1];  const float* b1a = (const float*)d_in[2];
    const float* w1b  = (const float*)d_in[3];  const float* b1b = (const float*)d_in[4];
    const float* w2a  = (const float*)d_in[5];  const float* b2a = (const float*)d_in[6];
    const float* w2b  = (const float*)d_in[7];  const float* b2b = (const float*)d_in[8];
    const float* w3a  = (const float*)d_in[9];  const float* b3a = (const float*)d_in[10];
    const float* w3b  = (const float*)d_in[11]; const float* b3b = (const float*)d_in[12];
    const float* w4a  = (const float*)d_in[13]; const float* b4a = (const float*)d_in[14];
    const float* w4b  = (const float*)d_in[15]; const float* b4b = (const float*)d_in[16];
    const float* fc1w = (const float*)d_in[17]; const float* fc1b = (const float*)d_in[18];
    const float* fc2w = (const float*)d_in[19]; const float* fc2b = (const float*)d_in[20];
    const float* gam  = (const float*)d_in[21]; const float* bet  = (const float*)d_in[22];
    float* out = (float*)d_out;

    char* ws = (char*)d_ws;
    size_t off = 0;
    auto alloc = [&](size_t bytes) -> void* {
        void* p = ws + off;
        off = (off + bytes + 255) & ~(size_t)255;
        return p;
    };
    float* nxyz1  = (float*)alloc((size_t)32 * 256 * 3 * 4);
    int*   gidx1  = (int*)  alloc((size_t)32 * 256 * 64 * 4);
    float* feats1 = (float*)alloc((size_t)32 * 256 * 128 * 4);
    float* nxyz2  = (float*)alloc((size_t)32 * 64 * 3 * 4);
    int*   gidx2  = (int*)  alloc((size_t)32 * 64 * 64 * 4);
    float* feats2 = (float*)alloc((size_t)32 * 64 * 256 * 4);
    float* nxyz3  = (float*)alloc((size_t)32 * 16 * 3 * 4);
    int*   gidx3  = (int*)  alloc((size_t)32 * 16 * 32 * 4);
    float* feats3 = (float*)alloc((size_t)32 * 16 * 512 * 4);
    float* g4     = (float*)alloc((size_t)32 * 1024 * 4);

    const float r2a = (float)(0.1 * 0.1);
    const float r2b = (float)(0.2 * 0.2);
    const float r2c = (float)(0.4 * 0.4);

    // ---- SA stage 1: N=4096 -> S=256, ns=64, 9 -> 64 -> 128
    fps_kernel<4096, 256, 6, 256><<<32, 256, 0, stream>>>(pc, nxyz1);
    bq_kernel<4096, 64, 6><<<(32 * 256 + 3) / 4, 256, 0, stream>>>(pc, nxyz1, gidx1, r2a, 256, 32 * 256);
    sa_mlp2_kernel<64, 9, 64, 128, 4096, 0><<<32 * 256, 256, 0, stream>>>(
        pc, pc, nxyz1, gidx1, w1a, b1a, w1b, b1b, feats1, 256);

    // ---- SA stage 2: N=256 -> S=64, ns=64, 131 -> 128 -> 256
    fps_kernel<256, 64, 3, 256><<<32, 256, 0, stream>>>(nxyz1, nxyz2);
    bq_kernel<256, 64, 3><<<(32 * 64 + 3) / 4, 256, 0, stream>>>(nxyz1, nxyz2, gidx2, r2b, 64, 32 * 64);
    sa_mlp2_kernel<64, 131, 128, 256, 256, 1><<<32 * 64, 256, 0, stream>>>(
        nxyz1, feats1, nxyz2, gidx2, w2a, b2a, w2b, b2b, feats2, 64);

    // ---- SA stage 3: N=64 -> S=16, ns=32, 259 -> 256 -> 512
    fps_kernel<64, 16, 3, 64><<<32, 64, 0, stream>>>(nxyz2, nxyz3);
    bq_kernel<64, 32, 3><<<(32 * 16 + 3) / 4, 256, 0, stream>>>(nxyz2, nxyz3, gidx3, r2c, 16, 32 * 16);
    sa_mlp2_kernel<32, 259, 256, 512, 64, 1><<<32 * 16, 256, 0, stream>>>(
        nxyz2, feats2, nxyz3, gidx3, w3a, b3a, w3b, b3b, feats3, 16);

    // ---- Head: per-batch 16-point MLP 515->512->1024 + maxpool(16)
    sa_mlp2_kernel<16, 515, 512, 1024, 16, 2><<<32, 256, 0, stream>>>(
        nxyz3, feats3, nullptr, nullptr, w4a, b4a, w4b, b4b, g4, 1);
    head2_kernel<<<32, 256, 0, stream>>>(g4, fc1w, fc1b, fc2w, fc2b, gam, bet, out);
}

// Round 5
// 1081.331 us; speedup vs baseline: 1.3806x; 1.0570x over previous
//
#include <hip/hip_runtime.h>

#define DEV static __device__ __forceinline__

DEV float sqdist(float dx, float dy, float dz) {
    // ((dx*dx + dy*dy) + dz*dz) with no FMA contraction — must match numpy f32
    return __fadd_rn(__fadd_rn(__fmul_rn(dx, dx), __fmul_rn(dy, dy)), __fmul_rn(dz, dz));
}

DEV void fma4(float4& acc, float h, const float4& w) {
    acc.x = fmaf(h, w.x, acc.x); acc.y = fmaf(h, w.y, acc.y);
    acc.z = fmaf(h, w.z, acc.z); acc.w = fmaf(h, w.w, acc.w);
}

// ---- argmax combine steps (value desc, index asc on ties) ----
template<int CTRL>
DEV int dpp_mov(int v) {
    return __builtin_amdgcn_update_dpp(v, v, CTRL, 0xF, 0xF, false);
}
template<int CTRL>
DEV void red_step_dpp(float& bv, int& bi) {
    float ov = __builtin_bit_cast(float, dpp_mov<CTRL>(__builtin_bit_cast(int, bv)));
    int   oi = dpp_mov<CTRL>(bi);
    if (ov > bv || (ov == bv && oi < bi)) { bv = ov; bi = oi; }
}

// ---------------- Farthest point sampling, v3 -----------------
// One block per batch. Coords in registers; float4 LDS copy for far-lookup.
// Per step: all-DPP wave argmax (xor levels + row_bcast15/31 -> lane 63),
// lane-63 leaders write ping-pong LDS slots, ONE barrier, redundant cross-wave
// reduce. Centroids buffered in LDS; global write once at the end (avoids the
// per-step vmcnt(0) drain hipcc emits before s_barrier).
template<int N, int NPOINT, int STRIDE, int T>
__global__ __launch_bounds__(T)
void fps_kernel(const float* __restrict__ xyz, float* __restrict__ new_xyz)
{
    constexpr int K  = (N + T - 1) / T;
    constexpr int NW = T / 64;
    const int b   = blockIdx.x;
    const int tid = threadIdx.x;
    __shared__ float4 pxyz[N];
    __shared__ float  sout[NPOINT * 3];
    __shared__ float  rv[2][(NW > 1) ? NW : 1];
    __shared__ int    ri[2][(NW > 1) ? NW : 1];

    const float* base = xyz + (size_t)b * N * STRIDE;
    float rx[K], ry[K], rz[K], d[K];
#pragma unroll
    for (int k = 0; k < K; ++k) {
        int p = tid + k * T;
        float x = 0.f, y = 0.f, z = 0.f;
        if (N % T == 0 || p < N) {
            x = base[p * STRIDE + 0];
            y = base[p * STRIDE + 1];
            z = base[p * STRIDE + 2];
            pxyz[p] = make_float4(x, y, z, 0.f);
        }
        rx[k] = x; ry[k] = y; rz[k] = z;
        d[k] = 1e10f;
    }
    __syncthreads();

    float4 c0v = pxyz[0];
    float cx = c0v.x, cy = c0v.y, cz = c0v.z;
    for (int s = 0; s < NPOINT; ++s) {
        if (tid == 0) { sout[s * 3 + 0] = cx; sout[s * 3 + 1] = cy; sout[s * 3 + 2] = cz; }
        float bestv = -1.0f; int besti = 0x7fffffff;
#pragma unroll
        for (int k = 0; k < K; ++k) {
            int p = tid + k * T;
            if (N % T == 0 || p < N) {
                float d2 = sqdist(rx[k] - cx, ry[k] - cy, rz[k] - cz);
                d[k] = fminf(d[k], d2);
                if (d[k] > bestv) { bestv = d[k]; besti = p; }  // k asc => lowest p on tie
            }
        }
        // wave all-reduce argmax, all-VALU: xor levels then row broadcasts.
        red_step_dpp<0xB1>(bestv, besti);    // quad_perm xor 1
        red_step_dpp<0x4E>(bestv, besti);    // quad_perm xor 2
        red_step_dpp<0x141>(bestv, besti);   // row_half_mirror (xor 4)
        red_step_dpp<0x140>(bestv, besti);   // row_mirror (xor 8)
        red_step_dpp<0x142>(bestv, besti);   // row_bcast15: rows 0->1, 2->3
        red_step_dpp<0x143>(bestv, besti);   // row_bcast31: lanes 48-63 full reduce
        // lane 63 now holds the wave's (max value, min index)

        int far;
        if constexpr (NW > 1) {
            const int sl = s & 1;
            if ((tid & 63) == 63) { rv[sl][tid >> 6] = bestv; ri[sl][tid >> 6] = besti; }
            __syncthreads();
            float bvv = rv[sl][0]; int bii = ri[sl][0];
#pragma unroll
            for (int q = 1; q < NW; ++q) {
                float qv = rv[sl][q]; int qi = ri[sl][q];
                if (qv > bvv || (qv == bvv && qi < bii)) { bvv = qv; bii = qi; }
            }
            far = bii;
        } else {
            far = __builtin_amdgcn_readlane(besti, 63);
        }
        float4 c = pxyz[far];
        cx = c.x; cy = c.y; cz = c.z;
    }
    __syncthreads();
    float* out = new_xyz + (size_t)b * NPOINT * 3;
    for (int i = tid; i < NPOINT * 3; i += T) out[i] = sout[i];
}

// ---------------- Ball query -----------------
template<int N, int NSAMP, int STRIDE>
__global__ __launch_bounds__(256)
void bq_kernel(const float* __restrict__ xyz, const float* __restrict__ newxyz,
               int* __restrict__ gidx, float r2, int S, int total)
{
    const int wid = blockIdx.x * 4 + (threadIdx.x >> 6);
    if (wid >= total) return;
    const int lane = threadIdx.x & 63;
    const int b = wid / S;
    const float cx = newxyz[(size_t)wid * 3 + 0];
    const float cy = newxyz[(size_t)wid * 3 + 1];
    const float cz = newxyz[(size_t)wid * 3 + 2];
    const float* base = xyz + (size_t)b * N * STRIDE;
    int* out = gidx + (size_t)wid * NSAMP;

    int count = 0, first = N - 1;
    constexpr int NCH = (N + 63) / 64;
    for (int ch = 0; ch < NCH; ++ch) {
        int p = ch * 64 + lane;
        bool pred = false;
        if (N % 64 == 0 || p < N) {
            float dx = base[p * STRIDE + 0] - cx;
            float dy = base[p * STRIDE + 1] - cy;
            float dz = base[p * STRIDE + 2] - cz;
            pred = sqdist(dx, dy, dz) < r2;
        }
        unsigned long long m = __ballot(pred);
        if (m) {
            if (count == 0) first = ch * 64 + __builtin_ctzll(m);
            int pos = count + __popcll(m & ((1ull << lane) - 1ull));
            if (pred && pos < NSAMP) out[pos] = p;
            count += __popcll(m);
            if (count >= NSAMP) break;
        }
    }
    if (count > NSAMP) count = NSAMP;
    for (int pos = count + lane; pos < NSAMP; pos += 64) out[pos] = first;
}

// ---------------- Grouped 2-layer MLP + maxpool, v3 -----------------
// MODE 0: stage1 (xyz stride 6, feats = pc permuted). MODE 1: feats array.
// MODE 2: head (no gather indices, no centroid subtraction).
// Phase B register tile: 4 points x 8 channels.
template<int NS, int CIN, int C1, int C2, int NSRC, int MODE>
__global__ __launch_bounds__(256)
void sa_mlp2_kernel(const float* __restrict__ sxyz, const float* __restrict__ sfeat,
                    const float* __restrict__ newxyz, const int* __restrict__ gidx,
                    const float* __restrict__ W1, const float* __restrict__ B1v,
                    const float* __restrict__ W2, const float* __restrict__ B2v,
                    float* __restrict__ outf, int S)
{
    constexpr int T    = 256;
    constexpr int KCC  = (CIN < 32) ? CIN : 32;            // k-chunk length
    constexpr int KCP0 = ((KCC + 3) / 4) * 4 + 4;
    constexpr int KCP  = ((KCP0 / 4) % 2 == 0) ? KCP0 + 4 : KCP0;  // odd quad stride
    constexpr int NPT  = NS / 4;
    constexpr int NCT1 = C1 / 4;
    constexpr int TPT  = (NPT * NCT1) / T;                 // phase-A tiles per thread
    constexpr int C1P  = C1 + 4;
    constexpr int CT2  = C2 / 8;                           // phase-B: 8 channels/thread
    constexpr int PB   = T / CT2;                          // phase-B parallel point-blocks
    constexpr int JP   = NPT / PB;                         // phase-B ptiles per thread
    constexpr int XS   = (MODE == 0) ? 6 : 3;
    constexpr int CF   = CIN - 3;
    static_assert(NS % 4 == 0 && C1 % 4 == 0 && C2 % 8 == 0, "");
    static_assert((NPT * NCT1) % T == 0 && TPT >= 1, "");
    static_assert(T % CT2 == 0 && NPT % PB == 0 && JP >= 1, "");

    __shared__ float xgc[NS][KCP];
    __shared__ __align__(16) float h1s[NS][C1P];
    __shared__ int   gix[NS];
    __shared__ float mpart[(PB > 1) ? PB * C2 : 8];

    const int g   = blockIdx.x;
    const int b   = g / S;
    const int tid = threadIdx.x;

    float ctr0 = 0.f, ctr1 = 0.f, ctr2 = 0.f;
    if constexpr (MODE != 2) {
        ctr0 = newxyz[(size_t)g * 3 + 0];
        ctr1 = newxyz[(size_t)g * 3 + 1];
        ctr2 = newxyz[(size_t)g * 3 + 2];
        for (int i = tid; i < NS; i += T) gix[i] = gidx[(size_t)g * NS + i];
        __syncthreads();
    }

    // ---- Phase A: layer 1, K-chunked, accumulators in registers ----
    float4 acc[TPT][4];
#pragma unroll
    for (int j = 0; j < TPT; ++j) {
        const int tl = tid + j * T;
        const int ct = tl % NCT1;
        const float4 bb = *(const float4*)&B1v[ct * 4];
#pragma unroll
        for (int i = 0; i < 4; ++i) acc[j][i] = bb;
    }

    const int nchunk = (CIN + KCC - 1) / KCC;
    for (int cch = 0; cch < nchunk; ++cch) {
        const int k0 = cch * KCC;
        const int kcLen = (CIN - k0 < KCC) ? (CIN - k0) : KCC;
        if (cch > 0 || MODE == 2) __syncthreads();
        // gather chunk
        for (int idx = tid; idx < NS * kcLen; idx += T) {
            const int p = idx / kcLen, kk = idx - p * kcLen, k = k0 + kk;
            float v;
            if constexpr (MODE == 2) {
                v = (k < 3) ? sxyz[((size_t)g * NS + p) * 3 + k]
                            : sfeat[((size_t)g * NS + p) * CF + (k - 3)];
            } else {
                const int gi = gix[p];
                if (k < 3) {
                    const float c = (k == 0) ? ctr0 : ((k == 1) ? ctr1 : ctr2);
                    v = sxyz[((size_t)b * NSRC + gi) * XS + k] - c;
                } else if constexpr (MODE == 0) {
                    const int j2 = k - 3;
                    v = sfeat[((size_t)b * NSRC + gi) * 6 + (j2 < 3 ? 3 + j2 : j2 - 3)];
                } else {
                    v = sfeat[((size_t)b * NSRC + gi) * CF + (k - 3)];
                }
            }
            xgc[p][kk] = v;
        }
        __syncthreads();
        // compute chunk
#pragma unroll
        for (int j = 0; j < TPT; ++j) {
            const int tl = tid + j * T;
            const int pt = tl / NCT1, ct = tl % NCT1;
            const int p0 = pt * 4, c0 = ct * 4;
            int kk = 0;
            for (; kk + 4 <= kcLen; kk += 4) {
                const float4 xa = *(const float4*)&xgc[p0 + 0][kk];
                const float4 xb = *(const float4*)&xgc[p0 + 1][kk];
                const float4 xc = *(const float4*)&xgc[p0 + 2][kk];
                const float4 xd = *(const float4*)&xgc[p0 + 3][kk];
                const float4 w0 = *(const float4*)&W1[(size_t)(k0 + kk + 0) * C1 + c0];
                const float4 w1 = *(const float4*)&W1[(size_t)(k0 + kk + 1) * C1 + c0];
                const float4 w2 = *(const float4*)&W1[(size_t)(k0 + kk + 2) * C1 + c0];
                const float4 w3 = *(const float4*)&W1[(size_t)(k0 + kk + 3) * C1 + c0];
                fma4(acc[j][0], xa.x, w0); fma4(acc[j][0], xa.y, w1); fma4(acc[j][0], xa.z, w2); fma4(acc[j][0], xa.w, w3);
                fma4(acc[j][1], xb.x, w0); fma4(acc[j][1], xb.y, w1); fma4(acc[j][1], xb.z, w2); fma4(acc[j][1], xb.w, w3);
                fma4(acc[j][2], xc.x, w0); fma4(acc[j][2], xc.y, w1); fma4(acc[j][2], xc.z, w2); fma4(acc[j][2], xc.w, w3);
                fma4(acc[j][3], xd.x, w0); fma4(acc[j][3], xd.y, w1); fma4(acc[j][3], xd.z, w2); fma4(acc[j][3], xd.w, w3);
            }
            for (; kk < kcLen; ++kk) {
                const float4 w = *(const float4*)&W1[(size_t)(k0 + kk) * C1 + c0];
                fma4(acc[j][0], xgc[p0 + 0][kk], w);
                fma4(acc[j][1], xgc[p0 + 1][kk], w);
                fma4(acc[j][2], xgc[p0 + 2][kk], w);
                fma4(acc[j][3], xgc[p0 + 3][kk], w);
            }
        }
    }
    // write h1 (relu)
    __syncthreads();
#pragma unroll
    for (int j = 0; j < TPT; ++j) {
        const int tl = tid + j * T;
        const int pt = tl / NCT1, ct = tl % NCT1;
        const int p0 = pt * 4, c0 = ct * 4;
#pragma unroll
        for (int i = 0; i < 4; ++i) {
            float4 r;
            r.x = fmaxf(acc[j][i].x, 0.f); r.y = fmaxf(acc[j][i].y, 0.f);
            r.z = fmaxf(acc[j][i].z, 0.f); r.w = fmaxf(acc[j][i].w, 0.f);
            *(float4*)&h1s[p0 + i][c0] = r;
        }
    }
    __syncthreads();

    // ---- Phase B: layer 2 + maxpool, 4 pts x 8 ch tiles ----
    {
        const int ct = tid % CT2, pb = tid / CT2;
        const int c0 = ct * 8;
        const float4 bbA = *(const float4*)&B2v[c0];
        const float4 bbB = *(const float4*)&B2v[c0 + 4];
        float4 mA = make_float4(0.f, 0.f, 0.f, 0.f);   // relu>=0
        float4 mB = make_float4(0.f, 0.f, 0.f, 0.f);
#pragma unroll
        for (int jp = 0; jp < JP; ++jp) {
            const int p0 = (pb + jp * PB) * 4;
            float4 a0A = bbA, a1A = bbA, a2A = bbA, a3A = bbA;
            float4 a0B = bbB, a1B = bbB, a2B = bbB, a3B = bbB;
            for (int k = 0; k < C1; k += 4) {
                const float4 hA = *(const float4*)&h1s[p0 + 0][k];
                const float4 hB = *(const float4*)&h1s[p0 + 1][k];
                const float4 hC = *(const float4*)&h1s[p0 + 2][k];
                const float4 hD = *(const float4*)&h1s[p0 + 3][k];
                const float4 w0A = *(const float4*)&W2[(size_t)(k + 0) * C2 + c0];
                const float4 w0B = *(const float4*)&W2[(size_t)(k + 0) * C2 + c0 + 4];
                const float4 w1A = *(const float4*)&W2[(size_t)(k + 1) * C2 + c0];
                const float4 w1B = *(const float4*)&W2[(size_t)(k + 1) * C2 + c0 + 4];
                const float4 w2A = *(const float4*)&W2[(size_t)(k + 2) * C2 + c0];
                const float4 w2B = *(const float4*)&W2[(size_t)(k + 2) * C2 + c0 + 4];
                const float4 w3A = *(const float4*)&W2[(size_t)(k + 3) * C2 + c0];
                const float4 w3B = *(const float4*)&W2[(size_t)(k + 3) * C2 + c0 + 4];
                fma4(a0A, hA.x, w0A); fma4(a0A, hA.y, w1A); fma4(a0A, hA.z, w2A); fma4(a0A, hA.w, w3A);
                fma4(a0B, hA.x, w0B); fma4(a0B, hA.y, w1B); fma4(a0B, hA.z, w2B); fma4(a0B, hA.w, w3B);
                fma4(a1A, hB.x, w0A); fma4(a1A, hB.y, w1A); fma4(a1A, hB.z, w2A); fma4(a1A, hB.w, w3A);
                fma4(a1B, hB.x, w0B); fma4(a1B, hB.y, w1B); fma4(a1B, hB.z, w2B); fma4(a1B, hB.w, w3B);
                fma4(a2A, hC.x, w0A); fma4(a2A, hC.y, w1A); fma4(a2A, hC.z, w2A); fma4(a2A, hC.w, w3A);
                fma4(a2B, hC.x, w0B); fma4(a2B, hC.y, w1B); fma4(a2B, hC.z, w2B); fma4(a2B, hC.w, w3B);
                fma4(a3A, hD.x, w0A); fma4(a3A, hD.y, w1A); fma4(a3A, hD.z, w2A); fma4(a3A, hD.w, w3A);
                fma4(a3B, hD.x, w0B); fma4(a3B, hD.y, w1B); fma4(a3B, hD.z, w2B); fma4(a3B, hD.w, w3B);
            }
            mA.x = fmaxf(mA.x, fmaxf(fmaxf(a0A.x, a1A.x), fmaxf(a2A.x, a3A.x)));
            mA.y = fmaxf(mA.y, fmaxf(fmaxf(a0A.y, a1A.y), fmaxf(a2A.y, a3A.y)));
            mA.z = fmaxf(mA.z, fmaxf(fmaxf(a0A.z, a1A.z), fmaxf(a2A.z, a3A.z)));
            mA.w = fmaxf(mA.w, fmaxf(fmaxf(a0A.w, a1A.w), fmaxf(a2A.w, a3A.w)));
            mB.x = fmaxf(mB.x, fmaxf(fmaxf(a0B.x, a1B.x), fmaxf(a2B.x, a3B.x)));
            mB.y = fmaxf(mB.y, fmaxf(fmaxf(a0B.y, a1B.y), fmaxf(a2B.y, a3B.y)));
            mB.z = fmaxf(mB.z, fmaxf(fmaxf(a0B.z, a1B.z), fmaxf(a2B.z, a3B.z)));
            mB.w = fmaxf(mB.w, fmaxf(fmaxf(a0B.w, a1B.w), fmaxf(a2B.w, a3B.w)));
        }
        if constexpr (PB == 1) {
            *(float4*)&outf[(size_t)g * C2 + c0] = mA;
            *(float4*)&outf[(size_t)g * C2 + c0 + 4] = mB;
        } else {
            *(float4*)&mpart[pb * C2 + c0] = mA;
            *(float4*)&mpart[pb * C2 + c0 + 4] = mB;
            __syncthreads();
            for (int c = tid; c < C2; c += T) {
                float mm = mpart[c];
#pragma unroll
                for (int q = 1; q < PB; ++q) mm = fmaxf(mm, mpart[q * C2 + c]);
                outf[(size_t)g * C2 + c] = mm;
            }
        }
    }
}

// ---------------- Head part 2: fc1(relu) -> fc2 -> bn-ish -----------------
__global__ __launch_bounds__(256)
void head2_kernel(const float* __restrict__ g4,
                  const float* __restrict__ fc1w, const float* __restrict__ fc1b,
                  const float* __restrict__ fc2w, const float* __restrict__ fc2b,
                  const float* __restrict__ gamma, const float* __restrict__ beta,
                  float* __restrict__ out)
{
    const int b   = blockIdx.x;
    const int tid = threadIdx.x;
    __shared__ float gm[1024], g1[1024];
    for (int c = tid; c < 1024; c += 256) gm[c] = g4[(size_t)b * 1024 + c];
    __syncthreads();
    {
        const int c0 = tid * 4;
        float4 a = *(const float4*)&fc1b[c0];
#pragma unroll 4
        for (int k = 0; k < 1024; ++k) {
            const float4 w = *(const float4*)&fc1w[(size_t)k * 1024 + c0];
            fma4(a, gm[k], w);
        }
        g1[c0 + 0] = fmaxf(a.x, 0.f); g1[c0 + 1] = fmaxf(a.y, 0.f);
        g1[c0 + 2] = fmaxf(a.z, 0.f); g1[c0 + 3] = fmaxf(a.w, 0.f);
    }
    __syncthreads();
    if (tid < 128) {
        const float s = sqrtf(1.00001f);
        const int c = tid;
        float a = fc2b[c];
#pragma unroll 4
        for (int k = 0; k < 1024; ++k) a = fmaf(g1[k], fc2w[(size_t)k * 128 + c], a);
        out[(size_t)b * 128 + c] = (a / s) * gamma[c] + beta[c];
    }
}

// ---------------------------------------------------------------------------
extern "C" void kernel_launch(void* const* d_in, const int* in_sizes, int n_in,
                              void* d_out, int out_size, void* d_ws, size_t ws_size,
                              hipStream_t stream)
{
    const float* pc   = (const float*)d_in[0];
    const float* w1a  = (const float*)d_in[1];  const float* b1a = (const float*)d_in[2];
    const float* w1b  = (const float*)d_in[3];  const float* b1b = (const float*)d_in[4];
    const float* w2a  = (const float*)d_in[5];  const float* b2a = (const float*)d_in[6];
    const float* w2b  = (const float*)d_in[7];  const float* b2b = (const float*)d_in[8];
    const float* w3a  = (const float*)d_in[9];  const float* b3a = (const float*)d_in[10];
    const float* w3b  = (const float*)d_in[11]; const float* b3b = (const float*)d_in[12];
    const float* w4a  = (const float*)d_in[13]; const float* b4a = (const float*)d_in[14];
    const float* w4b  = (const float*)d_in[15]; const float* b4b = (const float*)d_in[16];
    const float* fc1w = (const float*)d_in[17]; const float* fc1b = (const float*)d_in[18];
    const float* fc2w = (const float*)d_in[19]; const float* fc2b = (const float*)d_in[20];
    const float* gam  = (const float*)d_in[21]; const float* bet  = (const float*)d_in[22];
    float* out = (float*)d_out;

    char* ws = (char*)d_ws;
    size_t off = 0;
    auto alloc = [&](size_t bytes) -> void* {
        void* p = ws + off;
        off = (off + bytes + 255) & ~(size_t)255;
        return p;
    };
    float* nxyz1  = (float*)alloc((size_t)32 * 256 * 3 * 4);
    int*   gidx1  = (int*)  alloc((size_t)32 * 256 * 64 * 4);
    float* feats1 = (float*)alloc((size_t)32 * 256 * 128 * 4);
    float* nxyz2  = (float*)alloc((size_t)32 * 64 * 3 * 4);
    int*   gidx2  = (int*)  alloc((size_t)32 * 64 * 64 * 4);
    float* feats2 = (float*)alloc((size_t)32 * 64 * 256 * 4);
    float* nxyz3  = (float*)alloc((size_t)32 * 16 * 3 * 4);
    int*   gidx3  = (int*)  alloc((size_t)32 * 16 * 32 * 4);
    float* feats3 = (float*)alloc((size_t)32 * 16 * 512 * 4);
    float* g4     = (float*)alloc((size_t)32 * 1024 * 4);

    const float r2a = (float)(0.1 * 0.1);
    const float r2b = (float)(0.2 * 0.2);
    const float r2c = (float)(0.4 * 0.4);

    // ---- SA stage 1: N=4096 -> S=256, ns=64, 9 -> 64 -> 128
    fps_kernel<4096, 256, 6, 256><<<32, 256, 0, stream>>>(pc, nxyz1);
    bq_kernel<4096, 64, 6><<<(32 * 256 + 3) / 4, 256, 0, stream>>>(pc, nxyz1, gidx1, r2a, 256, 32 * 256);
    sa_mlp2_kernel<64, 9, 64, 128, 4096, 0><<<32 * 256, 256, 0, stream>>>(
        pc, pc, nxyz1, gidx1, w1a, b1a, w1b, b1b, feats1, 256);

    // ---- SA stage 2: N=256 -> S=64, ns=64, 131 -> 128 -> 256
    fps_kernel<256, 64, 3, 256><<<32, 256, 0, stream>>>(nxyz1, nxyz2);
    bq_kernel<256, 64, 3><<<(32 * 64 + 3) / 4, 256, 0, stream>>>(nxyz1, nxyz2, gidx2, r2b, 64, 32 * 64);
    sa_mlp2_kernel<64, 131, 128, 256, 256, 1><<<32 * 64, 256, 0, stream>>>(
        nxyz1, feats1, nxyz2, gidx2, w2a, b2a, w2b, b2b, feats2, 64);

    // ---- SA stage 3: N=64 -> S=16, ns=32, 259 -> 256 -> 512
    fps_kernel<64, 16, 3, 64><<<32, 64, 0, stream>>>(nxyz2, nxyz3);
    bq_kernel<64, 32, 3><<<(32 * 16 + 3) / 4, 256, 0, stream>>>(nxyz2, nxyz3, gidx3, r2c, 16, 32 * 16);
    sa_mlp2_kernel<32, 259, 256, 512, 64, 1><<<32 * 16, 256, 0, stream>>>(
        nxyz2, feats2, nxyz3, gidx3, w3a, b3a, w3b, b3b, feats3, 16);

    // ---- Head: per-batch 16-point MLP 515->512->1024 + maxpool(16)
    sa_mlp2_kernel<16, 515, 512, 1024, 16, 2><<<32, 256, 0, stream>>>(
        nxyz3, feats3, nullptr, nullptr, w4a, b4a, w4b, b4b, g4, 1);
    head2_kernel<<<32, 256, 0, stream>>>(g4, fc1w, fc1b, fc2w, fc2b, gam, bet, out);
}